// Round 8
// baseline (1990.774 us; speedup 1.0000x reference)
//
#include <hip/hip_runtime.h>
#include <hip/hip_bf16.h>
#include <cstdint>

typedef unsigned short u16;
typedef unsigned short us8 __attribute__((ext_vector_type(8)));
typedef __bf16 bf16x8 __attribute__((ext_vector_type(8)));
typedef float f32x4 __attribute__((ext_vector_type(4)));

// ---------- helpers ----------
__device__ __forceinline__ float b2f(u16 u) {
    union { float f; uint32_t i; } x; x.i = ((uint32_t)u) << 16; return x.f;
}
__device__ __forceinline__ u16 f2b(float f) {
    uint32_t u = __float_as_uint(f);
    uint32_t r = (u + 0x7FFFu + ((u >> 16) & 1u)) >> 16;
    return (u16)r;
}
__device__ __forceinline__ float sigm(float x) { return 1.0f / (1.0f + __expf(-x)); }
__device__ __forceinline__ float ldv(const void* p, size_t i, int dt) {
    return dt ? b2f(((const u16*)p)[i]) : ((const float*)p)[i];
}

__device__ __forceinline__ float wave_sum(float v) {
#pragma unroll
    for (int o = 32; o > 0; o >>= 1) v += __shfl_xor(v, o, 64);
    return v;
}
__device__ __forceinline__ void block_reduce2(float& a, float& b, float* sm) {
    int tid = threadIdx.x, wid = tid >> 6, lane = tid & 63;
    float as = wave_sum(a), bs = wave_sum(b);
    __syncthreads();
    if (lane == 0) { sm[wid] = as; sm[8 + wid] = bs; }
    __syncthreads();
    a = sm[0] + sm[1] + sm[2] + sm[3];
    b = sm[8] + sm[9] + sm[10] + sm[11];
}

// 64-lane sum via DPP ladder; full sum lands in lane 63.
__device__ __forceinline__ float dpp_sum64(float x) {
    x += __int_as_float(__builtin_amdgcn_update_dpp(0, __float_as_int(x), 0x111, 0xf, 0xf, true)); // row_shr:1
    x += __int_as_float(__builtin_amdgcn_update_dpp(0, __float_as_int(x), 0x112, 0xf, 0xf, true)); // row_shr:2
    x += __int_as_float(__builtin_amdgcn_update_dpp(0, __float_as_int(x), 0x114, 0xf, 0xf, true)); // row_shr:4
    x += __int_as_float(__builtin_amdgcn_update_dpp(0, __float_as_int(x), 0x118, 0xf, 0xf, true)); // row_shr:8
    x += __int_as_float(__builtin_amdgcn_update_dpp(0, __float_as_int(x), 0x142, 0xa, 0xf, true)); // row_bcast:15
    x += __int_as_float(__builtin_amdgcn_update_dpp(0, __float_as_int(x), 0x143, 0xc, 0xf, true)); // row_bcast:31
    return x;
}

// ---------- probe: dtype (hdr[0]) + which big array is x (hdr[1]) ----------
__global__ void k_probe(const u16* __restrict__ a0, const u16* __restrict__ a1,
                        const u16* __restrict__ a2, int* __restrict__ hdr) {
    __shared__ int wcnt;
    __shared__ float part[256];
    __shared__ float mag[3];
    int tid = threadIdx.x;
    if (tid == 0) wcnt = 0;
    __syncthreads();
    const u16* arr[3] = { a0, a1, a2 };
    int wild = 0;
    for (int s = 0; s < 3; ++s)
        for (int i = tid; i < 4096; i += 256) {
            u16 u = arr[s][i];
            int e = (u >> 7) & 0xFF;
            float av = fabsf(b2f(u));
            if (e == 0xFF || av > 100.f) wild++;
        }
    atomicAdd(&wcnt, wild);
    __syncthreads();
    int dt = (wcnt < 96) ? 1 : 0;
    for (int s = 0; s < 3; ++s) {
        float m = 0.f;
        if (dt) { for (int i = tid; i < 4096; i += 256) m += fabsf(b2f(arr[s][i])); }
        else    { const float* f = (const float*)arr[s];
                  for (int i = tid; i < 2048; i += 256) m += fabsf(f[i]); }
        part[tid] = m; __syncthreads();
        if (tid == 0) { float t = 0; for (int i = 0; i < 256; ++i) t += part[i]; mag[s] = t; }
        __syncthreads();
    }
    if (tid == 0) {
        int xs = 0;
        if (mag[1] > mag[xs]) xs = 1;
        if (mag[2] > mag[xs]) xs = 2;   // x ~N(0,1) vs 0.02-scale weights
        hdr[0] = dt; hdr[1] = xs;
    }
}

// ---------- double layernorm: x -> resid bf16, hs bf16 ----------
__global__ __launch_bounds__(256) void k_ln_in(
    const void* __restrict__ xa, const void* __restrict__ xb, const void* __restrict__ xc,
    const void* __restrict__ pw, const void* __restrict__ pb,
    const void* __restrict__ aw, const void* __restrict__ ab,
    u16* __restrict__ resid, u16* __restrict__ hs, const int* __restrict__ hdr)
{
    __shared__ float sm[16];
    const int dt = hdr[0], xs = hdr[1];
    const void* x = (xs == 0) ? xa : (xs == 1 ? xb : xc);
    int tok = blockIdx.x, tid = threadIdx.x;
    int c = tid * 4;
    size_t off = (size_t)tok * 1024 + c;
    float v0, v1, v2, v3;
    if (dt) {
        ushort4 xv = *(const ushort4*)((const u16*)x + off);
        v0 = b2f(xv.x); v1 = b2f(xv.y); v2 = b2f(xv.z); v3 = b2f(xv.w);
    } else {
        float4 xv = *(const float4*)((const float*)x + off);
        v0 = xv.x; v1 = xv.y; v2 = xv.z; v3 = xv.w;
    }
    float s = v0 + v1 + v2 + v3;
    float q = v0*v0 + v1*v1 + v2*v2 + v3*v3;
    block_reduce2(s, q, sm);
    float mean = s * (1.f/1024.f);
    float var  = q * (1.f/1024.f) - mean*mean;
    float rs = rsqrtf(var + 1e-5f);
    float h0 = (v0-mean)*rs*ldv(pw,c+0,dt) + ldv(pb,c+0,dt);
    float h1 = (v1-mean)*rs*ldv(pw,c+1,dt) + ldv(pb,c+1,dt);
    float h2 = (v2-mean)*rs*ldv(pw,c+2,dt) + ldv(pb,c+2,dt);
    float h3 = (v3-mean)*rs*ldv(pw,c+3,dt) + ldv(pb,c+3,dt);
    ushort4 rv; rv.x = f2b(h0); rv.y = f2b(h1); rv.z = f2b(h2); rv.w = f2b(h3);
    *(ushort4*)(resid + off) = rv;
    float s2 = h0 + h1 + h2 + h3;
    float q2 = h0*h0 + h1*h1 + h2*h2 + h3*h3;
    block_reduce2(s2, q2, sm);
    float m2 = s2 * (1.f/1024.f);
    float vr2 = q2 * (1.f/1024.f) - m2*m2;
    float rs2 = rsqrtf(vr2 + 1e-5f);
    ushort4 o;
    o.x = f2b((h0-m2)*rs2*ldv(aw,c+0,dt) + ldv(ab,c+0,dt));
    o.y = f2b((h1-m2)*rs2*ldv(aw,c+1,dt) + ldv(ab,c+1,dt));
    o.z = f2b((h2-m2)*rs2*ldv(aw,c+2,dt) + ldv(ab,c+2,dt));
    o.w = f2b((h3-m2)*rs2*ldv(aw,c+3,dt) + ldv(ab,c+3,dt));
    *(ushort4*)(hs + off) = o;
}

// ---------- layernorm bf16(ws) -> bf16 ----------
__global__ __launch_bounds__(256) void k_ln_bf(
    const u16* __restrict__ in, const void* __restrict__ w, const void* __restrict__ b,
    u16* __restrict__ out, const int* __restrict__ hdr)
{
    __shared__ float sm[16];
    const int dt = hdr[0];
    int tok = blockIdx.x, tid = threadIdx.x;
    int c = tid * 4;
    size_t off = (size_t)tok * 1024 + c;
    ushort4 xv = *(const ushort4*)(in + off);
    float v0 = b2f(xv.x), v1 = b2f(xv.y), v2 = b2f(xv.z), v3 = b2f(xv.w);
    float s = v0 + v1 + v2 + v3;
    float q = v0*v0 + v1*v1 + v2*v2 + v3*v3;
    block_reduce2(s, q, sm);
    float mean = s * (1.f/1024.f);
    float var  = q * (1.f/1024.f) - mean*mean;
    float rs = rsqrtf(var + 1e-5f);
    ushort4 o;
    o.x = f2b((v0-mean)*rs*ldv(w,c+0,dt) + ldv(b,c+0,dt));
    o.y = f2b((v1-mean)*rs*ldv(w,c+1,dt) + ldv(b,c+1,dt));
    o.z = f2b((v2-mean)*rs*ldv(w,c+2,dt) + ldv(b,c+2,dt));
    o.w = f2b((v3-mean)*rs*ldv(w,c+3,dt) + ldv(b,c+3,dt));
    *(ushort4*)(out + off) = o;
}

// ---------- weight transpose: W[K][N] (f32|bf16) -> WT[N][K] bf16 ----------
__global__ __launch_bounds__(256) void k_tr(
    const void* __restrict__ W, int K, int N, u16* __restrict__ WT,
    const int* __restrict__ hdr)
{
    const int dt = hdr[0];
    __shared__ u16 t[32][33];
    int n0 = blockIdx.x * 32, k0 = blockIdx.y * 32;
    int tx = threadIdx.x & 31, ty = threadIdx.x >> 5;   // 32 x 8
#pragma unroll
    for (int r = 0; r < 32; r += 8) {
        int k = k0 + ty + r;
        t[ty + r][tx] = f2b(ldv(W, (size_t)k * N + n0 + tx, dt));  // f2b(b2f(u))==u
    }
    __syncthreads();
#pragma unroll
    for (int r = 0; r < 32; r += 8) {
        int n = n0 + ty + r;
        WT[(size_t)n * K + k0 + tx] = t[tx][ty + r];
    }
}

// ---------- VALU GEMM (kept for small-N lora up-projections) ----------
// modes: 1=raw 2=tanh 3=sigm
__global__ __launch_bounds__(256) void k_sgemm(
    const u16* __restrict__ A, int lda, const void* __restrict__ mixc,
    const void* __restrict__ Bm, int ldb,
    void* __restrict__ D, int ldd,
    int K, int mode,
    const void* __restrict__ bias,
    const u16* __restrict__ add, int ldadd, const int* __restrict__ hdr)
{
    __shared__ float As[64][17];
    __shared__ float Bs[16][65];
    const int dt = hdr[0];
    int tid = threadIdx.x;
    int m0 = blockIdx.y * 64, n0 = blockIdx.x * 64;
    int tx = tid & 15, ty = tid >> 4;
    float acc[4][4];
#pragma unroll
    for (int i = 0; i < 4; ++i)
#pragma unroll
        for (int j = 0; j < 4; ++j) acc[i][j] = 0.f;

    for (int kb = 0; kb < K; kb += 16) {
        for (int i = tid; i < 1024; i += 256) {
            int row = i >> 4, kc = i & 15;
            int gr = m0 + row;
            int c  = kb + kc;
            float cur = b2f(A[(size_t)gr * lda + c]);
            float val = cur;
            if (mixc) {
                float prev = (gr & 2047) ? b2f(A[(size_t)(gr - 1) * lda + c]) : 0.f;
                val = cur + (prev - cur) * ldv(mixc, c, dt);
            }
            As[row][kc] = val;
        }
        for (int i = tid; i < 1024; i += 256) {
            int kr = i >> 6, nc = i & 63;
            Bs[kr][nc] = ldv(Bm, (size_t)(kb + kr) * ldb + n0 + nc, dt);
        }
        __syncthreads();
#pragma unroll
        for (int kk = 0; kk < 16; ++kk) {
            float av[4], bv[4];
#pragma unroll
            for (int i = 0; i < 4; ++i) av[i] = As[ty*4 + i][kk];
#pragma unroll
            for (int j = 0; j < 4; ++j) bv[j] = Bs[kk][tx*4 + j];
#pragma unroll
            for (int i = 0; i < 4; ++i)
#pragma unroll
                for (int j = 0; j < 4; ++j)
                    acc[i][j] = fmaf(av[i], bv[j], acc[i][j]);
        }
        __syncthreads();
    }
#pragma unroll
    for (int i = 0; i < 4; ++i)
#pragma unroll
        for (int j = 0; j < 4; ++j) {
            int row = m0 + ty*4 + i;
            int col = n0 + tx*4 + j;
            float v = acc[i][j];
            size_t di = (size_t)row * ldd + col;
            float r;
            switch (mode) {
                default: r = v; break;
                case 2: r = tanhf(v); break;
                case 3: r = sigm(v); break;
            }
            ((u16*)D)[di] = f2b(r);
        }
}

// ---------- MFMA GEMM v2: D[M,N] = mix(A)[M,K] @ BT^T, bf16 in, f32 acc ----------
// m97-verified structure: BOTH operands staged as [row][contiguous k] and read
// with plain ds_read_b128 (bf16x8). BT is the pre-transposed weight [N][K] bf16.
// Any hardware k-permutation cancels because A/B staging is symmetric.
// Tile 128x128, 4 waves (2x2), BK=32, LDS stride 40 u16 (80B; 2-way aliasing = free).
// modes: 1=raw 4=exp(-0.6065*sigm(v+bias)) 5=sigm(v+bias) 6=F32 OUT v+add
//        7=relu^2 8=bf16 v+add
__global__ __launch_bounds__(256, 2) void k_mf(
    const u16* __restrict__ A, int lda, const void* __restrict__ mixc,
    const u16* __restrict__ BT,
    void* __restrict__ D, int ldd,
    int K, int mode,
    const void* __restrict__ bias,
    const u16* __restrict__ add, int ldadd, const int* __restrict__ hdr)
{
    __shared__ u16 As[128 * 40];     // 10240 B
    __shared__ u16 Bs[128 * 40];     // 10240 B
    const int dt = hdr[0];
    const int tid = threadIdx.x;
    const int m0 = blockIdx.y * 128, n0 = blockIdx.x * 128;
    const int wid = tid >> 6, lane = tid & 63;
    const int wr = wid >> 1, wc = wid & 1;
    const int lg = lane >> 4, lc = lane & 15;
    const int srow = tid >> 1, shalf = tid & 1;   // staging: 128 rows x 2 k-halves

    f32x4 acc[4][4];
#pragma unroll
    for (int i = 0; i < 4; ++i)
#pragma unroll
        for (int j = 0; j < 4; ++j) acc[i][j] = (f32x4)0.f;

    for (int kb = 0; kb < K; kb += 32) {
        // ---- stage A (mix fused): A[m0+srow][kb+16*shalf .. +16] ----
        {
            int gr = m0 + srow;
            const u16* ap = A + (size_t)gr * lda + kb + 16 * shalf;
            us8 c1 = *(const us8*)ap;
            us8 c2 = *(const us8*)(ap + 8);
            if (mixc) {
                const u16* pp = ap - ((gr & 2047) ? lda : 0);
                float pz = (gr & 2047) ? 1.f : 0.f;
                us8 p1 = *(const us8*)pp;
                us8 p2 = *(const us8*)(pp + 8);
                int kbase = kb + 16 * shalf;
#pragma unroll
                for (int e = 0; e < 8; ++e) {
                    float cu1 = b2f(c1[e]), cu2 = b2f(c2[e]);
                    c1[e] = f2b(cu1 + (pz * b2f(p1[e]) - cu1) * ldv(mixc, kbase + e, dt));
                    c2[e] = f2b(cu2 + (pz * b2f(p2[e]) - cu2) * ldv(mixc, kbase + 8 + e, dt));
                }
            }
            u16* dst = As + srow * 40 + 16 * shalf;
            *(us8*)dst = c1;
            *(us8*)(dst + 8) = c2;
        }
        // ---- stage B: BT[n0+srow][kb+16*shalf .. +16] (always bf16) ----
        {
            const u16* bp = BT + (size_t)(n0 + srow) * K + kb + 16 * shalf;
            u16* dst = Bs + srow * 40 + 16 * shalf;
            *(us8*)dst = *(const us8*)bp;
            *(us8*)(dst + 8) = *(const us8*)(bp + 8);
        }
        __syncthreads();
        // ---- fragment loads (plain ds_read_b128) ----
        bf16x8 af[4], bf[4];
#pragma unroll
        for (int fm = 0; fm < 4; ++fm) {
            const u16* p = As + (wr * 64 + fm * 16 + lc) * 40 + lg * 8;
            union { us8 s; bf16x8 v; } u;
            u.s = *(const us8*)p;
            af[fm] = u.v;
        }
#pragma unroll
        for (int fc = 0; fc < 4; ++fc) {
            const u16* p = Bs + (wc * 64 + fc * 16 + lc) * 40 + lg * 8;
            union { us8 s; bf16x8 v; } u;
            u.s = *(const us8*)p;
            bf[fc] = u.v;
        }
        // ---- 16 MFMAs ----
#pragma unroll
        for (int fm = 0; fm < 4; ++fm)
#pragma unroll
            for (int fc = 0; fc < 4; ++fc)
                acc[fm][fc] = __builtin_amdgcn_mfma_f32_16x16x32_bf16(
                    af[fm], bf[fc], acc[fm][fc], 0, 0, 0);
        __syncthreads();
    }

    // ---- epilogue: C/D map col = lane&15, row = (lane>>4)*4 + reg ----
#pragma unroll
    for (int fm = 0; fm < 4; ++fm)
#pragma unroll
        for (int fc = 0; fc < 4; ++fc)
#pragma unroll
            for (int r = 0; r < 4; ++r) {
                int row = m0 + wr * 64 + fm * 16 + lg * 4 + r;
                int col = n0 + wc * 64 + fc * 16 + lc;
                float v = acc[fm][fc][r];
                size_t di = (size_t)row * ldd + col;
                if (mode == 6) {
                    ((float*)D)[di] = v + b2f(add[(size_t)row * ldadd + col]);
                    continue;
                }
                float rr;
                switch (mode) {
                    default: rr = v; break;
                    case 4: rr = __expf(-0.6065306597126334f * sigm(v + ldv(bias, col, dt))); break;
                    case 5: rr = sigm(v + ldv(bias, col, dt)); break;
                    case 7: { float t = fmaxf(v, 0.f); rr = t * t; } break;
                    case 8: rr = v + b2f(add[(size_t)row * ldadd + col]); break;
                }
                ((u16*)D)[di] = f2b(rr);
            }
}

// ---------- per-head prep ----------
__global__ __launch_bounds__(256) void k_prep(
    u16* __restrict__ k_bf, const u16* __restrict__ a_buf,
    const void* __restrict__ k_k, const void* __restrict__ k_a,
    u16* __restrict__ av, u16* __restrict__ bv, const int* __restrict__ hdr)
{
    const int dt = hdr[0];
    int ht = blockIdx.x * 4 + (threadIdx.x >> 6);
    int j = threadIdx.x & 63;
    int tok = ht >> 4, h = ht & 15, n = h * 64 + j;
    size_t idx = (size_t)tok * 1024 + n;
    float kv = b2f(k_bf[idx]);
    float a  = b2f(a_buf[idx]);
    float kk = kv * ldv(k_k, n, dt);
    float ss = wave_sum(kk * kk);
    float den = fmaxf(sqrtf(ss), 1e-12f);
    float kkn = kk / den;
    k_bf[idx] = f2b(kv * (1.f + (a - 1.f) * ldv(k_a, n, dt)));
    av[idx] = f2b(-kkn);
    bv[idx] = f2b(kkn * a);
}

// ---------- recurrence v5: one WAVE per (b, h, column-PAIR) ----------
// R7 PMC: VALU-issue-bound (~91 inst/step/wave, 54% busy). The 5 lane-indexed
// streams (r,d,k,a,b) are identical for all value-columns of a (b,h) — so one
// wave now serves TWO columns: shared loads/converts, one u32 load covers both
// v's, one u32 store covers both o's. ~31 inst/step/column (2.9x cut) and two
// independent DPP chains interleave to fill the latency stalls.
// 256 blocks x 4 waves = 1024 waves (1/SIMD). XCD remap kept (FETCH 24.6MB).
__global__ __launch_bounds__(256) void k_rec(
    const u16* __restrict__ r_bf, const u16* __restrict__ dcy,
    const u16* __restrict__ km, const u16* __restrict__ v_bf,
    const u16* __restrict__ av, const u16* __restrict__ bv,
    u16* __restrict__ o_buf)
{
    const int T = 2048;
    int rq = blockIdx.x & 7, q = blockIdx.x >> 3;   // rq = xcd slot, q 0..31
    int wid = threadIdx.x >> 6, lane = threadIdx.x & 63;
    int bh = rq * 4 + (q >> 3);          // 0..31; all 8 blocks of a bh share an XCD
    int jj = (q & 7) * 4 + wid;          // 0..31 column pair -> cols 2jj, 2jj+1
    int b = bh >> 4, h = bh & 15;
    size_t base = (size_t)(b * T) * 1024 + h * 64 + lane;     // lane = key idx
    size_t vidx = (size_t)(b * T) * 512 + h * 32 + jj;        // u32 index (2 cols)
    size_t oidx = vidx;
    const uint32_t* v32 = (const uint32_t*)v_bf;
    uint32_t* o32 = (uint32_t*)o_buf;
    float S0 = 0.f, S1 = 0.f;
    u16 rv = r_bf[base], dv = dcy[base], kv = km[base];
    u16 avv = av[base], bvv = bv[base];
    uint32_t vv = v32[vidx];
#pragma unroll 2
    for (int t = 0; t < T; ++t) {
        float rf = b2f(rv), df = b2f(dv), kf = b2f(kv);
        float af = b2f(avv), bf_ = b2f(bvv);
        float vf0 = __uint_as_float(vv << 16);          // low bf16
        float vf1 = __uint_as_float(vv & 0xFFFF0000u);  // high bf16
        if (t + 1 < T) {            // prefetch t+1 (+2048B, fits imm offset)
            base += 1024; vidx += 512;
            rv = r_bf[base]; dv = dcy[base]; kv = km[base];
            avv = av[base]; bvv = bv[base];
            vv = v32[vidx];
        }
        float sa0 = dpp_sum64(af * S0);
        float sa1 = dpp_sum64(af * S1);
        float X0 = fmaf(kf, vf0, S0 * df);   // independent of sa; overlaps ladders
        float X1 = fmaf(kf, vf1, S1 * df);
        sa0 = __int_as_float(__builtin_amdgcn_readlane(__float_as_int(sa0), 63));
        sa1 = __int_as_float(__builtin_amdgcn_readlane(__float_as_int(sa1), 63));
        S0 = fmaf(bf_, sa0, X0);
        S1 = fmaf(bf_, sa1, X1);
        float o0 = dpp_sum64(rf * S0);
        float o1 = dpp_sum64(rf * S1);
        if (lane == 63)
            o32[oidx] = (uint32_t)f2b(o0) | ((uint32_t)f2b(o1) << 16);
        oidx += 512;
    }
}

// ---------- groupnorm + bonus + gate ----------
__global__ __launch_bounds__(256) void k_post(
    const u16* __restrict__ o_buf, const u16* __restrict__ r_bf,
    const u16* __restrict__ km, const u16* __restrict__ v_bf,
    const u16* __restrict__ g_buf, const void* __restrict__ r_k,
    const void* __restrict__ gnw, const void* __restrict__ gnb,
    u16* __restrict__ ao, const int* __restrict__ hdr)
{
    const int dt = hdr[0];
    int ht = blockIdx.x * 4 + (threadIdx.x >> 6);
    int j = threadIdx.x & 63;
    int tok = ht >> 4, h = ht & 15, n = h * 64 + j;
    size_t idx = (size_t)tok * 1024 + n;
    float o = b2f(o_buf[idx]);
    float mu = wave_sum(o) * (1.f/64.f);
    float d = o - mu;
    float var = wave_sum(d * d) * (1.f/64.f);
    float og = d * rsqrtf(var + 6.4e-4f) * ldv(gnw, n, dt) + ldv(gnb, n, dt);
    float r = b2f(r_bf[idx]), kmv = b2f(km[idx]), v = b2f(v_bf[idx]);
    float bonus = wave_sum(r * kmv * ldv(r_k, n, dt));
    float val = (og + bonus * v) * b2f(g_buf[idx]);
    ao[idx] = f2b(val);
}

// ---------- host ----------
extern "C" void kernel_launch(void* const* d_in, const int* in_sizes, int n_in,
                              void* d_out, int out_size, void* d_ws, size_t ws_size,
                              hipStream_t stream) {
    (void)in_sizes; (void)n_in; (void)out_size; (void)ws_size;
    const void* xP     = d_in[0];
    const void* pre_w  = d_in[1];
    const void* pre_b  = d_in[2];
    const void* attn_w = d_in[3];
    const void* attn_b = d_in[4];
    const void* ffn_w  = d_in[5];
    const void* ffn_b  = d_in[6];
    const void* x_r    = d_in[7];
    const void* x_w    = d_in[8];
    const void* x_k    = d_in[9];
    const void* x_v    = d_in[10];
    const void* x_a    = d_in[11];
    const void* x_g    = d_in[12];
    const void* W_r    = d_in[13];
    const void* W_k    = d_in[14];
    const void* W_v    = d_in[15];
    const void* W_o    = d_in[16];
    const void* w1     = d_in[17];
    const void* w2     = d_in[18];
    const void* w_b    = d_in[19];
    const void* a1     = d_in[20];
    const void* a2     = d_in[21];
    const void* a_b    = d_in[22];
    const void* g1     = d_in[23];
    const void* g2     = d_in[24];
    const void* k_k    = d_in[25];
    const void* k_a    = d_in[26];
    const void* r_k    = d_in[27];
    const void* gn_w   = d_in[28];
    const void* gn_b   = d_in[29];
    const void* ffn_xk = d_in[30];
    const void* WkeyP  = d_in[31];
    const void* WvalP  = d_in[32];

    char* ws = (char*)d_ws;
    const size_t SL = 8388608ull;          // [4096][1024] bf16 slab
    int* hdr    = (int*)(ws + 0);
    u16* hs     = (u16*)(ws + 4096 + SL*0);
    u16* resid1 = (u16*)(ws + 4096 + SL*1);
    u16* dcy    = (u16*)(ws + 4096 + SL*2);
    u16* r_bf   = (u16*)(ws + 4096 + SL*3);
    u16* k_bf   = (u16*)(ws + 4096 + SL*4);
    u16* v_bf   = (u16*)(ws + 4096 + SL*5);
    u16* av_bf  = (u16*)(ws + 4096 + SL*6);
    u16* bv_bf  = (u16*)(ws + 4096 + SL*7);
    u16* a_buf  = (u16*)(ws + 4096 + SL*8);
    u16* g_buf  = (u16*)(ws + 4096 + SL*9);
    u16* tmpw   = (u16*)(ws + 4096 + SL*10);
    u16* tmpa   = (u16*)(ws + 4096 + SL*10 + 524288);
    u16* tmpg   = (u16*)(ws + 4096 + SL*10 + 1048576);
    u16* wT     = (u16*)(ws + 4096 + SL*10 + 2097152);   // 8MB transpose scratch; peak ~90MB
    // overlays (later lifetimes)
    u16* o_buf  = a_buf;                   // a dead after k_prep
    u16* ao_in  = bv_bf;                   // bv dead after k_rec
    u16* hid2   = dcy;                     // dcy dead after k_rec
    u16* hs2    = hs;                      // hs dead after projections
    u16* ffh    = r_bf;                    // [4096,4096] bf16 over r,k,v,av (dead after k_post)

    dim3 blk(256);
    dim3 g1024(8, 32), g4096(32, 32);
    dim3 t1024(32, 32), tKey(128, 32), tVal(32, 128), t64(32, 2), t128(32, 4);
    k_probe<<<1, blk, 0, stream>>>((const u16*)xP, (const u16*)WkeyP, (const u16*)WvalP, hdr);
    k_ln_in<<<4096, blk, 0, stream>>>(xP, WkeyP, WvalP, pre_w, pre_b, attn_w, attn_b, resid1, hs, hdr);

    // attn projections (fused token-shift mix) -- MFMA with pre-transposed weights
    k_tr<<<t1024, blk, 0, stream>>>(W_r, 1024, 1024, wT, hdr);
    k_mf<<<g1024, blk, 0, stream>>>(hs, 1024, x_r, wT, r_bf, 1024, 1024, 1, nullptr, nullptr, 0, hdr);
    k_sgemm<<<dim3(1, 64), blk, 0, stream>>>(hs, 1024, x_w, w1,  64,   tmpw, 64,   1024, 2, nullptr, nullptr, 0, hdr);
    k_tr<<<t64, blk, 0, stream>>>(w2, 64, 1024, wT, hdr);
    k_mf<<<g1024, blk, 0, stream>>>(tmpw, 64, nullptr, wT, dcy, 1024, 64, 4, w_b, nullptr, 0, hdr);
    k_tr<<<t1024, blk, 0, stream>>>(W_k, 1024, 1024, wT, hdr);
    k_mf<<<g1024, blk, 0, stream>>>(hs, 1024, x_k, wT, k_bf, 1024, 1024, 1, nullptr, nullptr, 0, hdr);
    k_tr<<<t1024, blk, 0, stream>>>(W_v, 1024, 1024, wT, hdr);
    k_mf<<<g1024, blk, 0, stream>>>(hs, 1024, x_v, wT, v_bf, 1024, 1024, 1, nullptr, nullptr, 0, hdr);
    k_sgemm<<<dim3(1, 64), blk, 0, stream>>>(hs, 1024, x_a, a1,  64,   tmpa, 64,   1024, 1, nullptr, nullptr, 0, hdr);
    k_tr<<<t64, blk, 0, stream>>>(a2, 64, 1024, wT, hdr);
    k_mf<<<g1024, blk, 0, stream>>>(tmpa, 64, nullptr, wT, a_buf, 1024, 64, 5, a_b, nullptr, 0, hdr);
    k_sgemm<<<dim3(2, 64), blk, 0, stream>>>(hs, 1024, x_g, g1,  128,  tmpg, 128,  1024, 3, nullptr, nullptr, 0, hdr);
    k_tr<<<t128, blk, 0, stream>>>(g2, 128, 1024, wT, hdr);
    k_mf<<<g1024, blk, 0, stream>>>(tmpg, 128, nullptr, wT, g_buf, 1024, 128, 1, nullptr, nullptr, 0, hdr);

    k_prep<<<16384, blk, 0, stream>>>(k_bf, a_buf, k_k, k_a, av_bf, bv_bf, hdr);
    k_rec<<<256, blk, 0, stream>>>(r_bf, dcy, k_bf, v_bf, av_bf, bv_bf, o_buf);
    k_post<<<16384, blk, 0, stream>>>(o_buf, r_bf, k_bf, v_bf, g_buf, r_k, gn_w, gn_b, ao_in, hdr);

    // output projection + residual -> hid2 (bf16)
    k_tr<<<t1024, blk, 0, stream>>>(W_o, 1024, 1024, wT, hdr);
    k_mf<<<g1024, blk, 0, stream>>>(ao_in, 1024, nullptr, wT, hid2, 1024, 1024, 8, nullptr, resid1, 1024, hdr);

    // FFN; final GEMM writes FLOAT32 output
    k_ln_bf<<<4096, blk, 0, stream>>>(hid2, ffn_w, ffn_b, hs2, hdr);
    k_tr<<<tKey, blk, 0, stream>>>(WkeyP, 1024, 4096, wT, hdr);
    k_mf<<<g4096, blk, 0, stream>>>(hs2, 1024, ffn_xk, wT, ffh, 4096, 1024, 7, nullptr, nullptr, 0, hdr);
    k_tr<<<tVal, blk, 0, stream>>>(WvalP, 4096, 1024, wT, hdr);
    k_mf<<<g1024, blk, 0, stream>>>(ffh, 4096, nullptr, wT, (float*)d_out, 1024, 4096, 6, nullptr, hid2, 1024, hdr);
}

// Round 9
// 1911.751 us; speedup vs baseline: 1.0413x; 1.0413x over previous
//
#include <hip/hip_runtime.h>
#include <hip/hip_bf16.h>
#include <cstdint>

typedef unsigned short u16;
typedef unsigned short us8 __attribute__((ext_vector_type(8)));
typedef __bf16 bf16x8 __attribute__((ext_vector_type(8)));
typedef float f32x4 __attribute__((ext_vector_type(4)));

// ---------- helpers ----------
__device__ __forceinline__ float b2f(u16 u) {
    union { float f; uint32_t i; } x; x.i = ((uint32_t)u) << 16; return x.f;
}
__device__ __forceinline__ u16 f2b(float f) {
    uint32_t u = __float_as_uint(f);
    uint32_t r = (u + 0x7FFFu + ((u >> 16) & 1u)) >> 16;
    return (u16)r;
}
__device__ __forceinline__ float sigm(float x) { return 1.0f / (1.0f + __expf(-x)); }
__device__ __forceinline__ float ldv(const void* p, size_t i, int dt) {
    return dt ? b2f(((const u16*)p)[i]) : ((const float*)p)[i];
}

__device__ __forceinline__ float wave_sum(float v) {
#pragma unroll
    for (int o = 32; o > 0; o >>= 1) v += __shfl_xor(v, o, 64);
    return v;
}
__device__ __forceinline__ void block_reduce2(float& a, float& b, float* sm) {
    int tid = threadIdx.x, wid = tid >> 6, lane = tid & 63;
    float as = wave_sum(a), bs = wave_sum(b);
    __syncthreads();
    if (lane == 0) { sm[wid] = as; sm[8 + wid] = bs; }
    __syncthreads();
    a = sm[0] + sm[1] + sm[2] + sm[3];
    b = sm[8] + sm[9] + sm[10] + sm[11];
}

// 64-lane sum via DPP ladder; full sum lands in lane 63.
__device__ __forceinline__ float dpp_sum64(float x) {
    x += __int_as_float(__builtin_amdgcn_update_dpp(0, __float_as_int(x), 0x111, 0xf, 0xf, true)); // row_shr:1
    x += __int_as_float(__builtin_amdgcn_update_dpp(0, __float_as_int(x), 0x112, 0xf, 0xf, true)); // row_shr:2
    x += __int_as_float(__builtin_amdgcn_update_dpp(0, __float_as_int(x), 0x114, 0xf, 0xf, true)); // row_shr:4
    x += __int_as_float(__builtin_amdgcn_update_dpp(0, __float_as_int(x), 0x118, 0xf, 0xf, true)); // row_shr:8
    x += __int_as_float(__builtin_amdgcn_update_dpp(0, __float_as_int(x), 0x142, 0xa, 0xf, true)); // row_bcast:15
    x += __int_as_float(__builtin_amdgcn_update_dpp(0, __float_as_int(x), 0x143, 0xc, 0xf, true)); // row_bcast:31
    return x;
}

// ---------- probe: dtype (hdr[0]) + which big array is x (hdr[1]) ----------
__global__ void k_probe(const u16* __restrict__ a0, const u16* __restrict__ a1,
                        const u16* __restrict__ a2, int* __restrict__ hdr) {
    __shared__ int wcnt;
    __shared__ float part[256];
    __shared__ float mag[3];
    int tid = threadIdx.x;
    if (tid == 0) wcnt = 0;
    __syncthreads();
    const u16* arr[3] = { a0, a1, a2 };
    int wild = 0;
    for (int s = 0; s < 3; ++s)
        for (int i = tid; i < 4096; i += 256) {
            u16 u = arr[s][i];
            int e = (u >> 7) & 0xFF;
            float av = fabsf(b2f(u));
            if (e == 0xFF || av > 100.f) wild++;
        }
    atomicAdd(&wcnt, wild);
    __syncthreads();
    int dt = (wcnt < 96) ? 1 : 0;
    for (int s = 0; s < 3; ++s) {
        float m = 0.f;
        if (dt) { for (int i = tid; i < 4096; i += 256) m += fabsf(b2f(arr[s][i])); }
        else    { const float* f = (const float*)arr[s];
                  for (int i = tid; i < 2048; i += 256) m += fabsf(f[i]); }
        part[tid] = m; __syncthreads();
        if (tid == 0) { float t = 0; for (int i = 0; i < 256; ++i) t += part[i]; mag[s] = t; }
        __syncthreads();
    }
    if (tid == 0) {
        int xs = 0;
        if (mag[1] > mag[xs]) xs = 1;
        if (mag[2] > mag[xs]) xs = 2;   // x ~N(0,1) vs 0.02-scale weights
        hdr[0] = dt; hdr[1] = xs;
    }
}

// ---------- double layernorm: x -> resid bf16, hs bf16 ----------
__global__ __launch_bounds__(256) void k_ln_in(
    const void* __restrict__ xa, const void* __restrict__ xb, const void* __restrict__ xc,
    const void* __restrict__ pw, const void* __restrict__ pb,
    const void* __restrict__ aw, const void* __restrict__ ab,
    u16* __restrict__ resid, u16* __restrict__ hs, const int* __restrict__ hdr)
{
    __shared__ float sm[16];
    const int dt = hdr[0], xs = hdr[1];
    const void* x = (xs == 0) ? xa : (xs == 1 ? xb : xc);
    int tok = blockIdx.x, tid = threadIdx.x;
    int c = tid * 4;
    size_t off = (size_t)tok * 1024 + c;
    float v0, v1, v2, v3;
    if (dt) {
        ushort4 xv = *(const ushort4*)((const u16*)x + off);
        v0 = b2f(xv.x); v1 = b2f(xv.y); v2 = b2f(xv.z); v3 = b2f(xv.w);
    } else {
        float4 xv = *(const float4*)((const float*)x + off);
        v0 = xv.x; v1 = xv.y; v2 = xv.z; v3 = xv.w;
    }
    float s = v0 + v1 + v2 + v3;
    float q = v0*v0 + v1*v1 + v2*v2 + v3*v3;
    block_reduce2(s, q, sm);
    float mean = s * (1.f/1024.f);
    float var  = q * (1.f/1024.f) - mean*mean;
    float rs = rsqrtf(var + 1e-5f);
    float h0 = (v0-mean)*rs*ldv(pw,c+0,dt) + ldv(pb,c+0,dt);
    float h1 = (v1-mean)*rs*ldv(pw,c+1,dt) + ldv(pb,c+1,dt);
    float h2 = (v2-mean)*rs*ldv(pw,c+2,dt) + ldv(pb,c+2,dt);
    float h3 = (v3-mean)*rs*ldv(pw,c+3,dt) + ldv(pb,c+3,dt);
    ushort4 rv; rv.x = f2b(h0); rv.y = f2b(h1); rv.z = f2b(h2); rv.w = f2b(h3);
    *(ushort4*)(resid + off) = rv;
    float s2 = h0 + h1 + h2 + h3;
    float q2 = h0*h0 + h1*h1 + h2*h2 + h3*h3;
    block_reduce2(s2, q2, sm);
    float m2 = s2 * (1.f/1024.f);
    float vr2 = q2 * (1.f/1024.f) - m2*m2;
    float rs2 = rsqrtf(vr2 + 1e-5f);
    ushort4 o;
    o.x = f2b((h0-m2)*rs2*ldv(aw,c+0,dt) + ldv(ab,c+0,dt));
    o.y = f2b((h1-m2)*rs2*ldv(aw,c+1,dt) + ldv(ab,c+1,dt));
    o.z = f2b((h2-m2)*rs2*ldv(aw,c+2,dt) + ldv(ab,c+2,dt));
    o.w = f2b((h3-m2)*rs2*ldv(aw,c+3,dt) + ldv(ab,c+3,dt));
    *(ushort4*)(hs + off) = o;
}

// ---------- layernorm bf16(ws) -> bf16 ----------
__global__ __launch_bounds__(256) void k_ln_bf(
    const u16* __restrict__ in, const void* __restrict__ w, const void* __restrict__ b,
    u16* __restrict__ out, const int* __restrict__ hdr)
{
    __shared__ float sm[16];
    const int dt = hdr[0];
    int tok = blockIdx.x, tid = threadIdx.x;
    int c = tid * 4;
    size_t off = (size_t)tok * 1024 + c;
    ushort4 xv = *(const ushort4*)(in + off);
    float v0 = b2f(xv.x), v1 = b2f(xv.y), v2 = b2f(xv.z), v3 = b2f(xv.w);
    float s = v0 + v1 + v2 + v3;
    float q = v0*v0 + v1*v1 + v2*v2 + v3*v3;
    block_reduce2(s, q, sm);
    float mean = s * (1.f/1024.f);
    float var  = q * (1.f/1024.f) - mean*mean;
    float rs = rsqrtf(var + 1e-5f);
    ushort4 o;
    o.x = f2b((v0-mean)*rs*ldv(w,c+0,dt) + ldv(b,c+0,dt));
    o.y = f2b((v1-mean)*rs*ldv(w,c+1,dt) + ldv(b,c+1,dt));
    o.z = f2b((v2-mean)*rs*ldv(w,c+2,dt) + ldv(b,c+2,dt));
    o.w = f2b((v3-mean)*rs*ldv(w,c+3,dt) + ldv(b,c+3,dt));
    *(ushort4*)(out + off) = o;
}

// ---------- weight transpose: W[K][N] (f32|bf16) -> WT[N][K] bf16 ----------
__global__ __launch_bounds__(256) void k_tr(
    const void* __restrict__ W, int K, int N, u16* __restrict__ WT,
    const int* __restrict__ hdr)
{
    const int dt = hdr[0];
    __shared__ u16 t[32][33];
    int n0 = blockIdx.x * 32, k0 = blockIdx.y * 32;
    int tx = threadIdx.x & 31, ty = threadIdx.x >> 5;   // 32 x 8
#pragma unroll
    for (int r = 0; r < 32; r += 8) {
        int k = k0 + ty + r;
        t[ty + r][tx] = f2b(ldv(W, (size_t)k * N + n0 + tx, dt));  // f2b(b2f(u))==u
    }
    __syncthreads();
#pragma unroll
    for (int r = 0; r < 32; r += 8) {
        int n = n0 + ty + r;
        WT[(size_t)n * K + k0 + tx] = t[tx][ty + r];
    }
}

// ---------- VALU GEMM (kept for small-N lora up-projections) ----------
// modes: 1=raw 2=tanh 3=sigm
__global__ __launch_bounds__(256) void k_sgemm(
    const u16* __restrict__ A, int lda, const void* __restrict__ mixc,
    const void* __restrict__ Bm, int ldb,
    void* __restrict__ D, int ldd,
    int K, int mode,
    const void* __restrict__ bias,
    const u16* __restrict__ add, int ldadd, const int* __restrict__ hdr)
{
    __shared__ float As[64][17];
    __shared__ float Bs[16][65];
    const int dt = hdr[0];
    int tid = threadIdx.x;
    int m0 = blockIdx.y * 64, n0 = blockIdx.x * 64;
    int tx = tid & 15, ty = tid >> 4;
    float acc[4][4];
#pragma unroll
    for (int i = 0; i < 4; ++i)
#pragma unroll
        for (int j = 0; j < 4; ++j) acc[i][j] = 0.f;

    for (int kb = 0; kb < K; kb += 16) {
        for (int i = tid; i < 1024; i += 256) {
            int row = i >> 4, kc = i & 15;
            int gr = m0 + row;
            int c  = kb + kc;
            float cur = b2f(A[(size_t)gr * lda + c]);
            float val = cur;
            if (mixc) {
                float prev = (gr & 2047) ? b2f(A[(size_t)(gr - 1) * lda + c]) : 0.f;
                val = cur + (prev - cur) * ldv(mixc, c, dt);
            }
            As[row][kc] = val;
        }
        for (int i = tid; i < 1024; i += 256) {
            int kr = i >> 6, nc = i & 63;
            Bs[kr][nc] = ldv(Bm, (size_t)(kb + kr) * ldb + n0 + nc, dt);
        }
        __syncthreads();
#pragma unroll
        for (int kk = 0; kk < 16; ++kk) {
            float av[4], bv[4];
#pragma unroll
            for (int i = 0; i < 4; ++i) av[i] = As[ty*4 + i][kk];
#pragma unroll
            for (int j = 0; j < 4; ++j) bv[j] = Bs[kk][tx*4 + j];
#pragma unroll
            for (int i = 0; i < 4; ++i)
#pragma unroll
                for (int j = 0; j < 4; ++j)
                    acc[i][j] = fmaf(av[i], bv[j], acc[i][j]);
        }
        __syncthreads();
    }
#pragma unroll
    for (int i = 0; i < 4; ++i)
#pragma unroll
        for (int j = 0; j < 4; ++j) {
            int row = m0 + ty*4 + i;
            int col = n0 + tx*4 + j;
            float v = acc[i][j];
            size_t di = (size_t)row * ldd + col;
            float r;
            switch (mode) {
                default: r = v; break;
                case 2: r = tanhf(v); break;
                case 3: r = sigm(v); break;
            }
            ((u16*)D)[di] = f2b(r);
        }
}

// ---------- shared epilogue for MFMA GEMMs ----------
__device__ __forceinline__ void mf_epi(
    void* D, int ldd, int mode, const void* bias,
    const u16* add, int ldadd, int dt,
    int row, int col, float v)
{
    size_t di = (size_t)row * ldd + col;
    if (mode == 6) {
        ((float*)D)[di] = v + b2f(add[(size_t)row * ldadd + col]);
        return;
    }
    float rr;
    switch (mode) {
        default: rr = v; break;
        case 4: rr = __expf(-0.6065306597126334f * sigm(v + ldv(bias, col, dt))); break;
        case 5: rr = sigm(v + ldv(bias, col, dt)); break;
        case 7: { float t = fmaxf(v, 0.f); rr = t * t; } break;
        case 8: rr = v + b2f(add[(size_t)row * ldadd + col]); break;
    }
    ((u16*)D)[di] = f2b(rr);
}

// ---------- MFMA GEMM: 128x128 tile (for N=4096 outputs; 4 blocks/CU there) ----------
// m97-verified structure: BOTH operands staged as [row][contiguous k], read with
// plain ds_read_b128. BT = pre-transposed weight [N][K] bf16. Symmetric staging
// cancels any HW k-permutation. LDS stride 40 u16 (2-way aliasing = free).
// modes: 1=raw 4=exp(-0.6065*sigm(v+bias)) 5=sigm(v+bias) 6=F32 OUT v+add
//        7=relu^2 8=bf16 v+add
__global__ __launch_bounds__(256, 2) void k_mf(
    const u16* __restrict__ A, int lda, const void* __restrict__ mixc,
    const u16* __restrict__ BT,
    void* __restrict__ D, int ldd,
    int K, int mode,
    const void* __restrict__ bias,
    const u16* __restrict__ add, int ldadd, const int* __restrict__ hdr)
{
    __shared__ u16 As[128 * 40];     // 10240 B
    __shared__ u16 Bs[128 * 40];     // 10240 B
    const int dt = hdr[0];
    const int tid = threadIdx.x;
    const int m0 = blockIdx.y * 128, n0 = blockIdx.x * 128;
    const int wid = tid >> 6, lane = tid & 63;
    const int wr = wid >> 1, wc = wid & 1;
    const int lg = lane >> 4, lc = lane & 15;
    const int srow = tid >> 1, shalf = tid & 1;   // staging: 128 rows x 2 k-halves

    f32x4 acc[4][4];
#pragma unroll
    for (int i = 0; i < 4; ++i)
#pragma unroll
        for (int j = 0; j < 4; ++j) acc[i][j] = (f32x4)0.f;

    for (int kb = 0; kb < K; kb += 32) {
        {
            int gr = m0 + srow;
            const u16* ap = A + (size_t)gr * lda + kb + 16 * shalf;
            us8 c1 = *(const us8*)ap;
            us8 c2 = *(const us8*)(ap + 8);
            if (mixc) {
                const u16* pp = ap - ((gr & 2047) ? lda : 0);
                float pz = (gr & 2047) ? 1.f : 0.f;
                us8 p1 = *(const us8*)pp;
                us8 p2 = *(const us8*)(pp + 8);
                int kbase = kb + 16 * shalf;
#pragma unroll
                for (int e = 0; e < 8; ++e) {
                    float cu1 = b2f(c1[e]), cu2 = b2f(c2[e]);
                    c1[e] = f2b(cu1 + (pz * b2f(p1[e]) - cu1) * ldv(mixc, kbase + e, dt));
                    c2[e] = f2b(cu2 + (pz * b2f(p2[e]) - cu2) * ldv(mixc, kbase + 8 + e, dt));
                }
            }
            u16* dst = As + srow * 40 + 16 * shalf;
            *(us8*)dst = c1;
            *(us8*)(dst + 8) = c2;
        }
        {
            const u16* bp = BT + (size_t)(n0 + srow) * K + kb + 16 * shalf;
            u16* dst = Bs + srow * 40 + 16 * shalf;
            *(us8*)dst = *(const us8*)bp;
            *(us8*)(dst + 8) = *(const us8*)(bp + 8);
        }
        __syncthreads();
        bf16x8 af[4], bf[4];
#pragma unroll
        for (int fm = 0; fm < 4; ++fm) {
            const u16* p = As + (wr * 64 + fm * 16 + lc) * 40 + lg * 8;
            union { us8 s; bf16x8 v; } u;
            u.s = *(const us8*)p;
            af[fm] = u.v;
        }
#pragma unroll
        for (int fc = 0; fc < 4; ++fc) {
            const u16* p = Bs + (wc * 64 + fc * 16 + lc) * 40 + lg * 8;
            union { us8 s; bf16x8 v; } u;
            u.s = *(const us8*)p;
            bf[fc] = u.v;
        }
#pragma unroll
        for (int fm = 0; fm < 4; ++fm)
#pragma unroll
            for (int fc = 0; fc < 4; ++fc)
                acc[fm][fc] = __builtin_amdgcn_mfma_f32_16x16x32_bf16(
                    af[fm], bf[fc], acc[fm][fc], 0, 0, 0);
        __syncthreads();
    }

#pragma unroll
    for (int fm = 0; fm < 4; ++fm)
#pragma unroll
        for (int fc = 0; fc < 4; ++fc)
#pragma unroll
            for (int r = 0; r < 4; ++r)
                mf_epi(D, ldd, mode, bias, add, ldadd, dt,
                       m0 + wr * 64 + fm * 16 + lg * 4 + r,
                       n0 + wc * 64 + fc * 16 + lc, acc[fm][fc][r]);
}

// ---------- MFMA GEMM: 64x64 tile (for N=1024 outputs) ----------
// R8 diagnosis: 128^2 tile at N=1024 -> 256 blocks = 1 block/CU, staging
// latency fully exposed (no inter-block overlap). 64^2 tile -> 1024 blocks =
// 4 blocks/CU. Same staging/fragment/epilogue logic, same K-step order
// (bit-identical output). Wave computes 32x32 (2x2 frags).
__global__ __launch_bounds__(256, 4) void k_mf64(
    const u16* __restrict__ A, int lda, const void* __restrict__ mixc,
    const u16* __restrict__ BT,
    void* __restrict__ D, int ldd,
    int K, int mode,
    const void* __restrict__ bias,
    const u16* __restrict__ add, int ldadd, const int* __restrict__ hdr)
{
    __shared__ u16 As[64 * 40];      // 5120 B
    __shared__ u16 Bs[64 * 40];      // 5120 B
    const int dt = hdr[0];
    const int tid = threadIdx.x;
    const int m0 = blockIdx.y * 64, n0 = blockIdx.x * 64;
    const int wid = tid >> 6, lane = tid & 63;
    const int wr = wid >> 1, wc = wid & 1;
    const int lg = lane >> 4, lc = lane & 15;
    const int srow = tid >> 2, sq = tid & 3;      // staging: 64 rows x 4 k-quarters

    f32x4 acc[2][2];
#pragma unroll
    for (int i = 0; i < 2; ++i)
#pragma unroll
        for (int j = 0; j < 2; ++j) acc[i][j] = (f32x4)0.f;

    for (int kb = 0; kb < K; kb += 32) {
        {
            int gr = m0 + srow;
            const u16* ap = A + (size_t)gr * lda + kb + 8 * sq;
            us8 c1 = *(const us8*)ap;
            if (mixc) {
                const u16* pp = ap - ((gr & 2047) ? lda : 0);
                float pz = (gr & 2047) ? 1.f : 0.f;
                us8 p1 = *(const us8*)pp;
                int kbase = kb + 8 * sq;
#pragma unroll
                for (int e = 0; e < 8; ++e) {
                    float cu = b2f(c1[e]);
                    c1[e] = f2b(cu + (pz * b2f(p1[e]) - cu) * ldv(mixc, kbase + e, dt));
                }
            }
            *(us8*)(As + srow * 40 + 8 * sq) = c1;
        }
        {
            const u16* bp = BT + (size_t)(n0 + srow) * K + kb + 8 * sq;
            *(us8*)(Bs + srow * 40 + 8 * sq) = *(const us8*)bp;
        }
        __syncthreads();
        bf16x8 af[2], bf[2];
#pragma unroll
        for (int fm = 0; fm < 2; ++fm) {
            const u16* p = As + (wr * 32 + fm * 16 + lc) * 40 + lg * 8;
            union { us8 s; bf16x8 v; } u;
            u.s = *(const us8*)p;
            af[fm] = u.v;
        }
#pragma unroll
        for (int fc = 0; fc < 2; ++fc) {
            const u16* p = Bs + (wc * 32 + fc * 16 + lc) * 40 + lg * 8;
            union { us8 s; bf16x8 v; } u;
            u.s = *(const us8*)p;
            bf[fc] = u.v;
        }
#pragma unroll
        for (int fm = 0; fm < 2; ++fm)
#pragma unroll
            for (int fc = 0; fc < 2; ++fc)
                acc[fm][fc] = __builtin_amdgcn_mfma_f32_16x16x32_bf16(
                    af[fm], bf[fc], acc[fm][fc], 0, 0, 0);
        __syncthreads();
    }

#pragma unroll
    for (int fm = 0; fm < 2; ++fm)
#pragma unroll
        for (int fc = 0; fc < 2; ++fc)
#pragma unroll
            for (int r = 0; r < 4; ++r)
                mf_epi(D, ldd, mode, bias, add, ldadd, dt,
                       m0 + wr * 32 + fm * 16 + lg * 4 + r,
                       n0 + wc * 32 + fc * 16 + lc, acc[fm][fc][r]);
}

// ---------- per-head prep ----------
__global__ __launch_bounds__(256) void k_prep(
    u16* __restrict__ k_bf, const u16* __restrict__ a_buf,
    const void* __restrict__ k_k, const void* __restrict__ k_a,
    u16* __restrict__ av, u16* __restrict__ bv, const int* __restrict__ hdr)
{
    const int dt = hdr[0];
    int ht = blockIdx.x * 4 + (threadIdx.x >> 6);
    int j = threadIdx.x & 63;
    int tok = ht >> 4, h = ht & 15, n = h * 64 + j;
    size_t idx = (size_t)tok * 1024 + n;
    float kv = b2f(k_bf[idx]);
    float a  = b2f(a_buf[idx]);
    float kk = kv * ldv(k_k, n, dt);
    float ss = wave_sum(kk * kk);
    float den = fmaxf(sqrtf(ss), 1e-12f);
    float kkn = kk / den;
    k_bf[idx] = f2b(kv * (1.f + (a - 1.f) * ldv(k_a, n, dt)));
    av[idx] = f2b(-kkn);
    bv[idx] = f2b(kkn * a);
}

// ---------- recurrence v5: one WAVE per (b, h, column-PAIR) ----------
__global__ __launch_bounds__(256) void k_rec(
    const u16* __restrict__ r_bf, const u16* __restrict__ dcy,
    const u16* __restrict__ km, const u16* __restrict__ v_bf,
    const u16* __restrict__ av, const u16* __restrict__ bv,
    u16* __restrict__ o_buf)
{
    const int T = 2048;
    int rq = blockIdx.x & 7, q = blockIdx.x >> 3;
    int wid = threadIdx.x >> 6, lane = threadIdx.x & 63;
    int bh = rq * 4 + (q >> 3);
    int jj = (q & 7) * 4 + wid;
    int b = bh >> 4, h = bh & 15;
    size_t base = (size_t)(b * T) * 1024 + h * 64 + lane;
    size_t vidx = (size_t)(b * T) * 512 + h * 32 + jj;
    size_t oidx = vidx;
    const uint32_t* v32 = (const uint32_t*)v_bf;
    uint32_t* o32 = (uint32_t*)o_buf;
    float S0 = 0.f, S1 = 0.f;
    u16 rv = r_bf[base], dv = dcy[base], kv = km[base];
    u16 avv = av[base], bvv = bv[base];
    uint32_t vv = v32[vidx];
#pragma unroll 2
    for (int t = 0; t < T; ++t) {
        float rf = b2f(rv), df = b2f(dv), kf = b2f(kv);
        float af = b2f(avv), bf_ = b2f(bvv);
        float vf0 = __uint_as_float(vv << 16);
        float vf1 = __uint_as_float(vv & 0xFFFF0000u);
        if (t + 1 < T) {
            base += 1024; vidx += 512;
            rv = r_bf[base]; dv = dcy[base]; kv = km[base];
            avv = av[base]; bvv = bv[base];
            vv = v32[vidx];
        }
        float sa0 = dpp_sum64(af * S0);
        float sa1 = dpp_sum64(af * S1);
        float X0 = fmaf(kf, vf0, S0 * df);
        float X1 = fmaf(kf, vf1, S1 * df);
        sa0 = __int_as_float(__builtin_amdgcn_readlane(__float_as_int(sa0), 63));
        sa1 = __int_as_float(__builtin_amdgcn_readlane(__float_as_int(sa1), 63));
        S0 = fmaf(bf_, sa0, X0);
        S1 = fmaf(bf_, sa1, X1);
        float o0 = dpp_sum64(rf * S0);
        float o1 = dpp_sum64(rf * S1);
        if (lane == 63)
            o32[oidx] = (uint32_t)f2b(o0) | ((uint32_t)f2b(o1) << 16);
        oidx += 512;
    }
}

// ---------- groupnorm + bonus + gate ----------
__global__ __launch_bounds__(256) void k_post(
    const u16* __restrict__ o_buf, const u16* __restrict__ r_bf,
    const u16* __restrict__ km, const u16* __restrict__ v_bf,
    const u16* __restrict__ g_buf, const void* __restrict__ r_k,
    const void* __restrict__ gnw, const void* __restrict__ gnb,
    u16* __restrict__ ao, const int* __restrict__ hdr)
{
    const int dt = hdr[0];
    int ht = blockIdx.x * 4 + (threadIdx.x >> 6);
    int j = threadIdx.x & 63;
    int tok = ht >> 4, h = ht & 15, n = h * 64 + j;
    size_t idx = (size_t)tok * 1024 + n;
    float o = b2f(o_buf[idx]);
    float mu = wave_sum(o) * (1.f/64.f);
    float d = o - mu;
    float var = wave_sum(d * d) * (1.f/64.f);
    float og = d * rsqrtf(var + 6.4e-4f) * ldv(gnw, n, dt) + ldv(gnb, n, dt);
    float r = b2f(r_bf[idx]), kmv = b2f(km[idx]), v = b2f(v_bf[idx]);
    float bonus = wave_sum(r * kmv * ldv(r_k, n, dt));
    float val = (og + bonus * v) * b2f(g_buf[idx]);
    ao[idx] = f2b(val);
}

// ---------- host ----------
extern "C" void kernel_launch(void* const* d_in, const int* in_sizes, int n_in,
                              void* d_out, int out_size, void* d_ws, size_t ws_size,
                              hipStream_t stream) {
    (void)in_sizes; (void)n_in; (void)out_size; (void)ws_size;
    const void* xP     = d_in[0];
    const void* pre_w  = d_in[1];
    const void* pre_b  = d_in[2];
    const void* attn_w = d_in[3];
    const void* attn_b = d_in[4];
    const void* ffn_w  = d_in[5];
    const void* ffn_b  = d_in[6];
    const void* x_r    = d_in[7];
    const void* x_w    = d_in[8];
    const void* x_k    = d_in[9];
    const void* x_v    = d_in[10];
    const void* x_a    = d_in[11];
    const void* x_g    = d_in[12];
    const void* W_r    = d_in[13];
    const void* W_k    = d_in[14];
    const void* W_v    = d_in[15];
    const void* W_o    = d_in[16];
    const void* w1     = d_in[17];
    const void* w2     = d_in[18];
    const void* w_b    = d_in[19];
    const void* a1     = d_in[20];
    const void* a2     = d_in[21];
    const void* a_b    = d_in[22];
    const void* g1     = d_in[23];
    const void* g2     = d_in[24];
    const void* k_k    = d_in[25];
    const void* k_a    = d_in[26];
    const void* r_k    = d_in[27];
    const void* gn_w   = d_in[28];
    const void* gn_b   = d_in[29];
    const void* ffn_xk = d_in[30];
    const void* WkeyP  = d_in[31];
    const void* WvalP  = d_in[32];

    char* ws = (char*)d_ws;
    const size_t SL = 8388608ull;          // [4096][1024] bf16 slab
    int* hdr    = (int*)(ws + 0);
    u16* hs     = (u16*)(ws + 4096 + SL*0);
    u16* resid1 = (u16*)(ws + 4096 + SL*1);
    u16* dcy    = (u16*)(ws + 4096 + SL*2);
    u16* r_bf   = (u16*)(ws + 4096 + SL*3);
    u16* k_bf   = (u16*)(ws + 4096 + SL*4);
    u16* v_bf   = (u16*)(ws + 4096 + SL*5);
    u16* av_bf  = (u16*)(ws + 4096 + SL*6);
    u16* bv_bf  = (u16*)(ws + 4096 + SL*7);
    u16* a_buf  = (u16*)(ws + 4096 + SL*8);
    u16* g_buf  = (u16*)(ws + 4096 + SL*9);
    u16* tmpw   = (u16*)(ws + 4096 + SL*10);
    u16* tmpa   = (u16*)(ws + 4096 + SL*10 + 524288);
    u16* tmpg   = (u16*)(ws + 4096 + SL*10 + 1048576);
    u16* wT     = (u16*)(ws + 4096 + SL*10 + 2097152);   // 8MB transpose scratch; peak ~90MB
    // overlays (later lifetimes)
    u16* o_buf  = a_buf;                   // a dead after k_prep
    u16* ao_in  = bv_bf;                   // bv dead after k_rec
    u16* hid2   = dcy;                     // dcy dead after k_rec
    u16* hs2    = hs;                      // hs dead after projections
    u16* ffh    = r_bf;                    // [4096,4096] bf16 over r,k,v,av (dead after k_post)

    dim3 blk(256);
    dim3 gm64(16, 64);                     // 64x64-tile grid for N=1024 (1024 blocks)
    dim3 g4096(32, 32);
    dim3 t1024(32, 32), tKey(128, 32), tVal(32, 128), t64(32, 2), t128(32, 4);
    k_probe<<<1, blk, 0, stream>>>((const u16*)xP, (const u16*)WkeyP, (const u16*)WvalP, hdr);
    k_ln_in<<<4096, blk, 0, stream>>>(xP, WkeyP, WvalP, pre_w, pre_b, attn_w, attn_b, resid1, hs, hdr);

    // attn projections (fused token-shift mix) -- MFMA 64^2 tiles (4 blocks/CU)
    k_tr<<<t1024, blk, 0, stream>>>(W_r, 1024, 1024, wT, hdr);
    k_mf64<<<gm64, blk, 0, stream>>>(hs, 1024, x_r, wT, r_bf, 1024, 1024, 1, nullptr, nullptr, 0, hdr);
    k_sgemm<<<dim3(1, 64), blk, 0, stream>>>(hs, 1024, x_w, w1,  64,   tmpw, 64,   1024, 2, nullptr, nullptr, 0, hdr);
    k_tr<<<t64, blk, 0, stream>>>(w2, 64, 1024, wT, hdr);
    k_mf64<<<gm64, blk, 0, stream>>>(tmpw, 64, nullptr, wT, dcy, 1024, 64, 4, w_b, nullptr, 0, hdr);
    k_tr<<<t1024, blk, 0, stream>>>(W_k, 1024, 1024, wT, hdr);
    k_mf64<<<gm64, blk, 0, stream>>>(hs, 1024, x_k, wT, k_bf, 1024, 1024, 1, nullptr, nullptr, 0, hdr);
    k_tr<<<t1024, blk, 0, stream>>>(W_v, 1024, 1024, wT, hdr);
    k_mf64<<<gm64, blk, 0, stream>>>(hs, 1024, x_v, wT, v_bf, 1024, 1024, 1, nullptr, nullptr, 0, hdr);
    k_sgemm<<<dim3(1, 64), blk, 0, stream>>>(hs, 1024, x_a, a1,  64,   tmpa, 64,   1024, 1, nullptr, nullptr, 0, hdr);
    k_tr<<<t64, blk, 0, stream>>>(a2, 64, 1024, wT, hdr);
    k_mf64<<<gm64, blk, 0, stream>>>(tmpa, 64, nullptr, wT, a_buf, 1024, 64, 5, a_b, nullptr, 0, hdr);
    k_sgemm<<<dim3(2, 64), blk, 0, stream>>>(hs, 1024, x_g, g1,  128,  tmpg, 128,  1024, 3, nullptr, nullptr, 0, hdr);
    k_tr<<<t128, blk, 0, stream>>>(g2, 128, 1024, wT, hdr);
    k_mf64<<<gm64, blk, 0, stream>>>(tmpg, 128, nullptr, wT, g_buf, 1024, 128, 1, nullptr, nullptr, 0, hdr);

    k_prep<<<16384, blk, 0, stream>>>(k_bf, a_buf, k_k, k_a, av_bf, bv_bf, hdr);
    k_rec<<<256, blk, 0, stream>>>(r_bf, dcy, k_bf, v_bf, av_bf, bv_bf, o_buf);
    k_post<<<16384, blk, 0, stream>>>(o_buf, r_bf, k_bf, v_bf, g_buf, r_k, gn_w, gn_b, ao_in, hdr);

    // output projection + residual -> hid2 (bf16)
    k_tr<<<t1024, blk, 0, stream>>>(W_o, 1024, 1024, wT, hdr);
    k_mf64<<<gm64, blk, 0, stream>>>(ao_in, 1024, nullptr, wT, hid2, 1024, 1024, 8, nullptr, resid1, 1024, hdr);

    // FFN; final GEMM writes FLOAT32 output
    k_ln_bf<<<4096, blk, 0, stream>>>(hid2, ffn_w, ffn_b, hs2, hdr);
    k_tr<<<tKey, blk, 0, stream>>>(WkeyP, 1024, 4096, wT, hdr);
    k_mf<<<g4096, blk, 0, stream>>>(hs2, 1024, ffn_xk, wT, ffh, 4096, 1024, 7, nullptr, nullptr, 0, hdr);
    k_tr<<<tVal, blk, 0, stream>>>(WvalP, 4096, 1024, wT, hdr);
    k_mf64<<<gm64, blk, 0, stream>>>(ffh, 4096, nullptr, wT, (float*)d_out, 1024, 4096, 6, nullptr, hid2, 1024, hdr);
}